// Round 7
// baseline (139.600 us; speedup 1.0000x reference)
//
#include <hip/hip_runtime.h>

// MpMaxPoolingMatch: out[b,t,m] = tanh( max_s sum_d lt[b,t,d]*km[m,d]*rt[b,s,d] )
// B=32, T=256, D=512, MP=20.
// R6: VALU-debloat. R5 was VALU-issue-bound (VALUBusy 41% > MfmaUtil 28%): 8 mulpacks
// + dup A-scaling per s-split block. Now block = 64t x 256s(full), 4 waves of 64x64
// (acc[4][4]=64 AGPR, 3 waves/SIMD): A-scale = 4 mulpacks + 1 load + 1 ds_write per
// thread-step (half of R5), no duplication, B pure DMA, tanh fused back (no combine).
// Keeps XOR-swizzled slabs (0 conflicts) + XCD swizzle (L2-resident).

constexpr int TT = 256;   // T
constexpr int DD = 512;   // D
constexpr int NM = 20;    // MP
constexpr int NB = 32;    // B
constexpr int BM = 64;    // t-tile
constexpr int BN = 256;   // s (full)
constexpr int BK = 32;
constexpr int NK = DD / BK;   // 16

typedef short bf16x8 __attribute__((ext_vector_type(8)));
typedef float f32x4  __attribute__((ext_vector_type(4)));

__device__ __forceinline__ void async_ld16(const void* g, void* l) {
    __builtin_amdgcn_global_load_lds(
        (const __attribute__((address_space(1))) void*)g,
        (__attribute__((address_space(3))) void*)l, 16, 0, 0);
}

__device__ __forceinline__ unsigned pack_bf16(float lo, float hi) {
    unsigned ulo = __builtin_bit_cast(unsigned, lo);
    unsigned uhi = __builtin_bit_cast(unsigned, hi);
    return (ulo >> 16) | (uhi & 0xFFFF0000u);
}

// scale packed bf16 pair (lo=elem k, hi=elem k+1) by f32 k0,k1; repack (truncate)
__device__ __forceinline__ unsigned mulpack(unsigned a2, float k0, float k1) {
    float f0 = __builtin_bit_cast(float, a2 << 16) * k0;
    float f1 = __builtin_bit_cast(float, a2 & 0xFFFF0000u) * k1;
    return __builtin_amdgcn_perm(__builtin_bit_cast(unsigned, f1),
                                 __builtin_bit_cast(unsigned, f0), 0x07060302u);
}

// ---------------- Phase 1: coalesced fp32 -> bf16 cast, row-major ----------------
__global__ __launch_bounds__(256)
void cast_bf16(const float* __restrict__ lt, const float* __restrict__ rt,
               unsigned short* __restrict__ ltb, unsigned short* __restrict__ rtb)
{
    const int half = (int)gridDim.x >> 1;
    int bid = blockIdx.x;
    const float* src;
    unsigned short* dst;
    if (bid < half) { src = lt; dst = ltb; }
    else            { src = rt; dst = rtb; bid -= half; }
    size_t base = ((size_t)bid * 256 + threadIdx.x) * 8;
    float4 a = *(const float4*)(src + base);
    float4 b = *(const float4*)(src + base + 4);
    uint4 w;
    w.x = pack_bf16(a.x, a.y);
    w.y = pack_bf16(a.z, a.w);
    w.z = pack_bf16(b.x, b.y);
    w.w = pack_bf16(b.z, b.w);
    *(uint4*)(dst + base) = w;
}

// ---------------- Main kernel: 64t x 256s, 4 waves of 64x64 ----------------
__global__ __launch_bounds__(256, 3)
void mp_match_main(const unsigned short* __restrict__ ltb, const unsigned short* __restrict__ rtb,
                   const float* __restrict__ km, float* __restrict__ out)
{
    // chunk-indexed slabs: chunk = row*4 + pos, pos = c ^ ((row>>1)&3), 16B per chunk
    __shared__ __attribute__((aligned(16))) unsigned short Bsh[2][BN * 4 * 8]; // 32 KB
    __shared__ __attribute__((aligned(16))) unsigned short Ash[2][BM * 4 * 8]; // 8 KB
    __shared__ __attribute__((aligned(16))) float kmf[DD];                     // 2 KB
    __shared__ __attribute__((aligned(16))) float maxbuf[4][BM];               // 1 KB

    // XCD swizzle: flat%8 == XCD; b%8 == XCD -> each XCD L2 holds 4 b's tiles.
    const int f  = blockIdx.x;           // 0..2559
    const int c8 = f & 7;
    const int i  = f >> 3;               // 0..319
    const int b  = c8 + 8 * (i / 80);    // 0..31
    const int j  = i % 80;
    const int m  = j >> 2;               // 0..19
    const int t0 = (j & 3) * BM;         // 0,64,128,192

    const int tid  = threadIdx.x;
    const int w    = tid >> 6;           // wave = s-quarter
    const int lane = tid & 63;
    const int l15  = lane & 15;
    const int l4   = lane >> 4;
    const int wsO  = w * 64;             // wave's s offset

    kmf[tid]       = km[(size_t)m * DD + tid];
    kmf[tid + 256] = km[(size_t)m * DD + tid + 256];

    const unsigned short* ltB = ltb + ((size_t)b * TT + t0) * DD;
    const unsigned short* rtB = rtb + (size_t)b * TT * DD;

    // A staging: exactly 1 slot/thread. row=tid>>2 (0..63), c=tid&3.
    const int arow = tid >> 2, ac = tid & 3;
    const int apos = ac ^ ((arow >> 1) & 3);
    const unsigned short* aSrc = ltB + (size_t)arow * DD + ac * 8;

    auto issueB = [&](int kk, int buf) {
        const int kb = kk * BK;
#pragma unroll
        for (int q = 0; q < 4; ++q) {
            int slot = q * 256 + tid;
            int row = slot >> 2;
            int c = (slot & 3) ^ ((slot >> 3) & 3);   // (row>>1)&3 == (slot>>3)&3
            async_ld16(rtB + (size_t)row * DD + kb + c * 8,
                       (char*)&Bsh[buf][0] + (size_t)slot * 16);
        }
    };
    auto scaleWrite = [&](int kk, int buf, uint4 a) {
        float4 k0 = *(const float4*)&kmf[kk * BK + ac * 8];
        float4 k1 = *(const float4*)&kmf[kk * BK + ac * 8 + 4];
        uint4 o;
        o.x = mulpack(a.x, k0.x, k0.y);
        o.y = mulpack(a.y, k0.z, k0.w);
        o.z = mulpack(a.z, k1.x, k1.y);
        o.w = mulpack(a.w, k1.z, k1.w);
        *(uint4*)&Ash[buf][(size_t)(arow * 4 + apos) * 8] = o;
    };

    f32x4 acc[4][4] = {};
    uint4 ar;

    ar = *(const uint4*)(aSrc);
    issueB(0, 0);
    __syncthreads();       // kmf visible; prologue loads+DMA drained
    scaleWrite(0, 0, ar);

    const int fpos = l4 ^ ((l15 >> 1) & 3);

    for (int kk = 0; kk < NK; ++kk) {
        const int buf = kk & 1;
        __syncthreads();   // Ash/Bsh[buf] ready; prior reads of buf^1 drained
        if (kk + 1 < NK) {
            ar = *(const uint4*)(aSrc + (kk + 1) * BK);
            issueB(kk + 1, buf ^ 1);    // in flight through this step's MFMA
        }
        bf16x8 af[4], bv[4];
#pragma unroll
        for (int ii = 0; ii < 4; ++ii)
            af[ii] = *(const bf16x8*)&Ash[buf][(size_t)((ii * 16 + l15) * 4 + fpos) * 8];
#pragma unroll
        for (int jj = 0; jj < 4; ++jj)
            bv[jj] = *(const bf16x8*)&Bsh[buf][(size_t)((wsO + jj * 16 + l15) * 4 + fpos) * 8];
#pragma unroll
        for (int ii = 0; ii < 4; ++ii)
#pragma unroll
            for (int jj = 0; jj < 4; ++jj)
                acc[ii][jj] = __builtin_amdgcn_mfma_f32_16x16x32_bf16(af[ii], bv[jj], acc[ii][jj], 0, 0, 0);
        if (kk + 1 < NK)
            scaleWrite(kk + 1, buf ^ 1, ar);   // overlaps MFMA; done by next barrier
    }

    // ---- Epilogue: max over this wave's 64 s, cross-wave via maxbuf, tanh, store.
    // C layout: col(s)=lane&15, row(t)=(lane>>4)*4+reg.
#pragma unroll
    for (int ii = 0; ii < 4; ++ii) {
        f32x4 v = acc[ii][0];
#pragma unroll
        for (int jj = 1; jj < 4; ++jj) {
            v.x = fmaxf(v.x, acc[ii][jj].x);
            v.y = fmaxf(v.y, acc[ii][jj].y);
            v.z = fmaxf(v.z, acc[ii][jj].z);
            v.w = fmaxf(v.w, acc[ii][jj].w);
        }
#pragma unroll
        for (int off = 1; off < 16; off <<= 1) {
            v.x = fmaxf(v.x, __shfl_xor(v.x, off, 64));
            v.y = fmaxf(v.y, __shfl_xor(v.y, off, 64));
            v.z = fmaxf(v.z, __shfl_xor(v.z, off, 64));
            v.w = fmaxf(v.w, __shfl_xor(v.w, off, 64));
        }
        if (l15 == 0)
            *(f32x4*)&maxbuf[w][ii * 16 + l4 * 4] = v;
    }
    __syncthreads();
    if (tid < BM) {
        float v = fmaxf(fmaxf(maxbuf[0][tid], maxbuf[1][tid]),
                        fmaxf(maxbuf[2][tid], maxbuf[3][tid]));
        out[((size_t)b * TT + t0 + tid) * NM + m] = tanhf(v);
    }
}

// ---------------- R1 fallback (no workspace) ----------------
__global__ __launch_bounds__(256, 2)
void mp_match_kernel(const float* __restrict__ lt, const float* __restrict__ rt,
                     const float* __restrict__ km, float* __restrict__ out)
{
    __shared__ __attribute__((aligned(16))) unsigned short Ash[2][4][128][8];
    __shared__ __attribute__((aligned(16))) unsigned short Bsh2[2][4][BN][8];
    __shared__ __attribute__((aligned(16))) float maxbuf[2][128];

    const int ttile = blockIdx.x, m = blockIdx.y, b = blockIdx.z;
    const int t0 = ttile * 128;
    const int tid = threadIdx.x, wave = tid >> 6, lane = tid & 63;
    const int l15 = lane & 15, l4 = lane >> 4;
    const int wt = (wave & 1) * 64, wsi = wave >> 1;

    const float* ltp = lt + ((size_t)b * TT + t0) * DD;
    const float* rtp = rt + (size_t)b * TT * DD;
    const float* kmp = km + (size_t)m * DD;
    const int a_t = tid >> 1, a_h = tid & 1;

    f32x4 acc[4][8] = {};

    auto stage = [&](int kk, int buf) {
        const int d0 = kk * BK;
        const float* ap = ltp + (size_t)a_t * DD + d0 + a_h * 16;
        const float* kp = kmp + d0 + a_h * 16;
#pragma unroll
        for (int q = 0; q < 2; ++q) {
            float4 x0 = *(const float4*)(ap + q * 8);
            float4 x1 = *(const float4*)(ap + q * 8 + 4);
            float4 k0 = *(const float4*)(kp + q * 8);
            float4 k1 = *(const float4*)(kp + q * 8 + 4);
            uint4 wv;
            wv.x = pack_bf16(x0.x * k0.x, x0.y * k0.y);
            wv.y = pack_bf16(x0.z * k0.z, x0.w * k0.w);
            wv.z = pack_bf16(x1.x * k1.x, x1.y * k1.y);
            wv.w = pack_bf16(x1.z * k1.z, x1.w * k1.w);
            *(uint4*)&Ash[buf][a_h * 2 + q][a_t][0] = wv;
        }
        const float* bp = rtp + (size_t)tid * DD + d0;
#pragma unroll
        for (int p = 0; p < 4; ++p) {
            float4 y0 = *(const float4*)(bp + p * 8);
            float4 y1 = *(const float4*)(bp + p * 8 + 4);
            uint4 wv;
            wv.x = pack_bf16(y0.x, y0.y);
            wv.y = pack_bf16(y0.z, y0.w);
            wv.z = pack_bf16(y1.x, y1.y);
            wv.w = pack_bf16(y1.z, y1.w);
            *(uint4*)&Bsh2[buf][p][tid][0] = wv;
        }
    };

    stage(0, 0);
    for (int kk = 0; kk < NK; ++kk) {
        const int buf = kk & 1;
        __syncthreads();
        bf16x8 af[4], bfv[8];
#pragma unroll
        for (int i = 0; i < 4; ++i)
            af[i] = *(const bf16x8*)&Ash[buf][l4][wt + i * 16 + l15][0];
#pragma unroll
        for (int j = 0; j < 8; ++j)
            bfv[j] = *(const bf16x8*)&Bsh2[buf][l4][wsi * 128 + j * 16 + l15][0];
        if (kk + 1 < NK) stage(kk + 1, buf ^ 1);
#pragma unroll
        for (int i = 0; i < 4; ++i)
#pragma unroll
            for (int j = 0; j < 8; ++j)
                acc[i][j] = __builtin_amdgcn_mfma_f32_16x16x32_bf16(af[i], bfv[j], acc[i][j], 0, 0, 0);
    }
#pragma unroll
    for (int i = 0; i < 4; ++i) {
        f32x4 v = acc[i][0];
#pragma unroll
        for (int j = 1; j < 8; ++j) {
            v.x = fmaxf(v.x, acc[i][j].x); v.y = fmaxf(v.y, acc[i][j].y);
            v.z = fmaxf(v.z, acc[i][j].z); v.w = fmaxf(v.w, acc[i][j].w);
        }
#pragma unroll
        for (int off = 1; off < 16; off <<= 1) {
            v.x = fmaxf(v.x, __shfl_xor(v.x, off, 64));
            v.y = fmaxf(v.y, __shfl_xor(v.y, off, 64));
            v.z = fmaxf(v.z, __shfl_xor(v.z, off, 64));
            v.w = fmaxf(v.w, __shfl_xor(v.w, off, 64));
        }
        if (l15 == 0) *(f32x4*)&maxbuf[wsi][wt + i * 16 + l4 * 4] = v;
    }
    __syncthreads();
    if (tid < 128) {
        float v = fmaxf(maxbuf[0][tid], maxbuf[1][tid]);
        out[((size_t)b * TT + t0 + tid) * NM + m] = tanhf(v);
    }
}

extern "C" void kernel_launch(void* const* d_in, const int* in_sizes, int n_in,
                              void* d_out, int out_size, void* d_ws, size_t ws_size,
                              hipStream_t stream) {
    const float* lt  = (const float*)d_in[0];   // (32,256,512) fp32
    const float* rt  = (const float*)d_in[1];   // (32,256,512) fp32
    const float* km  = (const float*)d_in[2];   // (20,512) fp32
    float*       out = (float*)d_out;           // (32,256,20) fp32

    const size_t elems = (size_t)NB * TT * DD;                  // 4,194,304 per tensor
    const size_t castB = 2 * elems * sizeof(unsigned short);    // 16 MB

    if (ws_size >= castB) {
        unsigned short* ltb = (unsigned short*)d_ws;
        unsigned short* rtb = ltb + elems;
        cast_bf16<<<4096, 256, 0, stream>>>(lt, rt, ltb, rtb);
        mp_match_main<<<2560, 256, 0, stream>>>(ltb, rtb, km, out);
    } else {
        mp_match_kernel<<<dim3(2, NM, NB), 256, 0, stream>>>(lt, rt, km, out);
    }
}

// Round 8
// 133.913 us; speedup vs baseline: 1.0425x; 1.0425x over previous
//
#include <hip/hip_runtime.h>

// MpMaxPoolingMatch: out[b,t,m] = tanh( max_s sum_d lt[b,t,d]*km[m,d]*rt[b,s,d] )
// B=32, T=256, D=512, MP=20.
// R7: R5 structure (best measured: 128t x 128s s-split, acc[4][4]=64 AGPR, XOR-swizzled
// slabs, XCD swizzle, partial-max + combine) with __launch_bounds__(256,4):
// 60 VGPR + 64 AGPR = 124/wave <= 128 -> 4 waves/SIMD; LDS 35.8KB x 4 = 143KB <= 160KB
// -> 4 blocks/CU. R6's 64x256 geometry abandoned (doubled B-DMA/step, regressed).

constexpr int TT = 256;   // T
constexpr int DD = 512;   // D
constexpr int NM = 20;    // MP
constexpr int NB = 32;    // B
constexpr int BM = 128;
constexpr int BK = 32;
constexpr int NK = DD / BK;   // 16

typedef short bf16x8 __attribute__((ext_vector_type(8)));
typedef float f32x4  __attribute__((ext_vector_type(4)));

__device__ __forceinline__ void async_ld16(const void* g, void* l) {
    __builtin_amdgcn_global_load_lds(
        (const __attribute__((address_space(1))) void*)g,
        (__attribute__((address_space(3))) void*)l, 16, 0, 0);
}

__device__ __forceinline__ unsigned pack_bf16(float lo, float hi) {
    unsigned ulo = __builtin_bit_cast(unsigned, lo);
    unsigned uhi = __builtin_bit_cast(unsigned, hi);
    return (ulo >> 16) | (uhi & 0xFFFF0000u);
}

// scale packed bf16 pair (lo=elem k, hi=elem k+1) by f32 k0,k1; repack (truncate)
__device__ __forceinline__ unsigned mulpack(unsigned a2, float k0, float k1) {
    float f0 = __builtin_bit_cast(float, a2 << 16) * k0;
    float f1 = __builtin_bit_cast(float, a2 & 0xFFFF0000u) * k1;
    return __builtin_amdgcn_perm(__builtin_bit_cast(unsigned, f1),
                                 __builtin_bit_cast(unsigned, f0), 0x07060302u);
}

// ---------------- Phase 1: coalesced fp32 -> bf16 cast, row-major ----------------
__global__ __launch_bounds__(256)
void cast_bf16(const float* __restrict__ lt, const float* __restrict__ rt,
               unsigned short* __restrict__ ltb, unsigned short* __restrict__ rtb)
{
    const int half = (int)gridDim.x >> 1;
    int bid = blockIdx.x;
    const float* src;
    unsigned short* dst;
    if (bid < half) { src = lt; dst = ltb; }
    else            { src = rt; dst = rtb; bid -= half; }
    size_t base = ((size_t)bid * 256 + threadIdx.x) * 8;
    float4 a = *(const float4*)(src + base);
    float4 b = *(const float4*)(src + base + 4);
    uint4 w;
    w.x = pack_bf16(a.x, a.y);
    w.y = pack_bf16(a.z, a.w);
    w.z = pack_bf16(b.x, b.y);
    w.w = pack_bf16(b.z, b.w);
    *(uint4*)(dst + base) = w;
}

// ---------------- Split-s main kernel: 128x128 tile, partial max to ws ----------------
__global__ __launch_bounds__(256, 4)
void mp_match_split(const unsigned short* __restrict__ ltb, const unsigned short* __restrict__ rtb,
                    const float* __restrict__ km, float* __restrict__ part)
{
    // chunk-indexed slabs: chunk = row*4 + pos, pos = c ^ ((row>>1)&3), 16B per chunk
    __shared__ __attribute__((aligned(16))) unsigned short Ash[2][BM * 4 * 8]; // 16 KB
    __shared__ __attribute__((aligned(16))) unsigned short Bsh[2][BM * 4 * 8]; // 16 KB (128 s-rows)
    __shared__ __attribute__((aligned(16))) float kmf[DD];                     // 2 KB
    __shared__ __attribute__((aligned(16))) float maxbuf[2][BM];               // 1 KB

    // XCD swizzle: flat%8 == XCD; b%8 == XCD -> 4 b's (2 MB bf16) per XCD L2.
    const int f  = blockIdx.x;           // 0..2559
    const int c8 = f & 7;
    const int i  = f >> 3;               // 0..319
    const int b  = c8 + 8 * (i / 80);    // 0..31
    const int j  = i % 80;
    const int m  = j >> 2;               // 0..19
    const int t0 = ((j >> 1) & 1) * 128;
    const int s0 = (j & 1) * 128;
    const int sT = j & 1;

    const int tid  = threadIdx.x;
    const int w    = tid >> 6;
    const int lane = tid & 63;
    const int l15  = lane & 15;
    const int l4   = lane >> 4;
    const int wt   = (w & 1) * 64;       // wave's t offset
    const int wsO  = (w >> 1) * 64;      // wave's s offset within 128-tile

    kmf[tid]       = km[(size_t)m * DD + tid];
    kmf[tid + 256] = km[(size_t)m * DD + tid + 256];

    const unsigned short* ltB = ltb + ((size_t)b * TT + t0) * DD;
    const unsigned short* rtB = rtb + ((size_t)b * TT + s0) * DD;

    // A staging: thread handles chunks (row=slot>>2, c=slot&3) for slot=tid, tid+256.
    const int ar0 = tid >> 2,        ac = tid & 3;
    const int ar1 = (tid + 256) >> 2;
    const int ap0 = ac ^ ((ar0 >> 1) & 3);
    const int ap1 = ac ^ ((ar1 >> 1) & 3);
    const unsigned short* aSrc0 = ltB + (size_t)ar0 * DD + ac * 8;
    const unsigned short* aSrc1 = ltB + (size_t)ar1 * DD + ac * 8;

    auto issueB = [&](int kk, int buf) {
        const int kb = kk * BK;
#pragma unroll
        for (int q = 0; q < 2; ++q) {
            int slot = q * 256 + tid;
            int row = slot >> 2;
            int c = (slot & 3) ^ ((slot >> 3) & 3);
            async_ld16(rtB + (size_t)row * DD + kb + c * 8,
                       (char*)&Bsh[buf][0] + (size_t)slot * 16);
        }
    };
    auto aload = [&](int kk, uint4* ar) {
        ar[0] = *(const uint4*)(aSrc0 + kk * BK);
        ar[1] = *(const uint4*)(aSrc1 + kk * BK);
    };
    auto scaleWrite = [&](int kk, int buf, const uint4* ar) {
        float4 k0 = *(const float4*)&kmf[kk * BK + ac * 8];
        float4 k1 = *(const float4*)&kmf[kk * BK + ac * 8 + 4];
        uint4 o;
        o.x = mulpack(ar[0].x, k0.x, k0.y);
        o.y = mulpack(ar[0].y, k0.z, k0.w);
        o.z = mulpack(ar[0].z, k1.x, k1.y);
        o.w = mulpack(ar[0].w, k1.z, k1.w);
        *(uint4*)&Ash[buf][(size_t)(ar0 * 4 + ap0) * 8] = o;
        o.x = mulpack(ar[1].x, k0.x, k0.y);
        o.y = mulpack(ar[1].y, k0.z, k0.w);
        o.z = mulpack(ar[1].z, k1.x, k1.y);
        o.w = mulpack(ar[1].w, k1.z, k1.w);
        *(uint4*)&Ash[buf][(size_t)(ar1 * 4 + ap1) * 8] = o;
    };

    f32x4 acc[4][4] = {};
    uint4 ar[2];

    aload(0, ar);
    issueB(0, 0);
    __syncthreads();       // kmf visible; prologue loads+DMA drained
    scaleWrite(0, 0, ar);

    const int fpos = l4 ^ ((l15 >> 1) & 3);

    for (int kk = 0; kk < NK; ++kk) {
        const int buf = kk & 1;
        __syncthreads();
        if (kk + 1 < NK) {
            aload(kk + 1, ar);
            issueB(kk + 1, buf ^ 1);
        }
        bf16x8 af[4], bv[4];
#pragma unroll
        for (int ii = 0; ii < 4; ++ii)
            af[ii] = *(const bf16x8*)&Ash[buf][(size_t)((wt + ii * 16 + l15) * 4 + fpos) * 8];
#pragma unroll
        for (int jj = 0; jj < 4; ++jj)
            bv[jj] = *(const bf16x8*)&Bsh[buf][(size_t)((wsO + jj * 16 + l15) * 4 + fpos) * 8];
#pragma unroll
        for (int ii = 0; ii < 4; ++ii)
#pragma unroll
            for (int jj = 0; jj < 4; ++jj)
                acc[ii][jj] = __builtin_amdgcn_mfma_f32_16x16x32_bf16(af[ii], bv[jj], acc[ii][jj], 0, 0, 0);
        if (kk + 1 < NK)
            scaleWrite(kk + 1, buf ^ 1, ar);
    }

    // ---- Epilogue: max over this block's 128 s (NO tanh yet). C layout: col=lane&15, row=(lane>>4)*4+reg.
#pragma unroll
    for (int ii = 0; ii < 4; ++ii) {
        f32x4 v = acc[ii][0];
#pragma unroll
        for (int jj = 1; jj < 4; ++jj) {
            v.x = fmaxf(v.x, acc[ii][jj].x);
            v.y = fmaxf(v.y, acc[ii][jj].y);
            v.z = fmaxf(v.z, acc[ii][jj].z);
            v.w = fmaxf(v.w, acc[ii][jj].w);
        }
#pragma unroll
        for (int off = 1; off < 16; off <<= 1) {
            v.x = fmaxf(v.x, __shfl_xor(v.x, off, 64));
            v.y = fmaxf(v.y, __shfl_xor(v.y, off, 64));
            v.z = fmaxf(v.z, __shfl_xor(v.z, off, 64));
            v.w = fmaxf(v.w, __shfl_xor(v.w, off, 64));
        }
        if (l15 == 0)
            *(f32x4*)&maxbuf[w >> 1][wt + ii * 16 + l4 * 4] = v;
    }
    __syncthreads();
    if (tid < BM) {
        float v = fmaxf(maxbuf[0][tid], maxbuf[1][tid]);
        part[(((size_t)sT * NB + b) * TT + t0 + tid) * NM + m] = v;
    }
}

// ---------------- Combine: out = tanh(max(p0, p1)) ----------------
__global__ __launch_bounds__(256)
void mp_combine(const float* __restrict__ part, float* __restrict__ out, int n)
{
    int idx = blockIdx.x * 256 + threadIdx.x;
    if (idx < n)
        out[idx] = tanhf(fmaxf(part[idx], part[(size_t)n + idx]));
}

// ---------------- R1 fallback (no workspace) ----------------
__global__ __launch_bounds__(256, 2)
void mp_match_kernel(const float* __restrict__ lt, const float* __restrict__ rt,
                     const float* __restrict__ km, float* __restrict__ out)
{
    __shared__ __attribute__((aligned(16))) unsigned short Ash[2][4][128][8];
    __shared__ __attribute__((aligned(16))) unsigned short Bsh2[2][4][256][8];
    __shared__ __attribute__((aligned(16))) float maxbuf[2][128];

    const int ttile = blockIdx.x, m = blockIdx.y, b = blockIdx.z;
    const int t0 = ttile * 128;
    const int tid = threadIdx.x, wave = tid >> 6, lane = tid & 63;
    const int l15 = lane & 15, l4 = lane >> 4;
    const int wt = (wave & 1) * 64, wsi = wave >> 1;

    const float* ltp = lt + ((size_t)b * TT + t0) * DD;
    const float* rtp = rt + (size_t)b * TT * DD;
    const float* kmp = km + (size_t)m * DD;
    const int a_t = tid >> 1, a_h = tid & 1;

    f32x4 acc[4][8] = {};

    auto stage = [&](int kk, int buf) {
        const int d0 = kk * BK;
        const float* ap = ltp + (size_t)a_t * DD + d0 + a_h * 16;
        const float* kp = kmp + d0 + a_h * 16;
#pragma unroll
        for (int q = 0; q < 2; ++q) {
            float4 x0 = *(const float4*)(ap + q * 8);
            float4 x1 = *(const float4*)(ap + q * 8 + 4);
            float4 k0 = *(const float4*)(kp + q * 8);
            float4 k1 = *(const float4*)(kp + q * 8 + 4);
            uint4 wv;
            wv.x = pack_bf16(x0.x * k0.x, x0.y * k0.y);
            wv.y = pack_bf16(x0.z * k0.z, x0.w * k0.w);
            wv.z = pack_bf16(x1.x * k1.x, x1.y * k1.y);
            wv.w = pack_bf16(x1.z * k1.z, x1.w * k1.w);
            *(uint4*)&Ash[buf][a_h * 2 + q][a_t][0] = wv;
        }
        const float* bp = rtp + (size_t)tid * DD + d0;
#pragma unroll
        for (int p = 0; p < 4; ++p) {
            float4 y0 = *(const float4*)(bp + p * 8);
            float4 y1 = *(const float4*)(bp + p * 8 + 4);
            uint4 wv;
            wv.x = pack_bf16(y0.x, y0.y);
            wv.y = pack_bf16(y0.z, y0.w);
            wv.z = pack_bf16(y1.x, y1.y);
            wv.w = pack_bf16(y1.z, y1.w);
            *(uint4*)&Bsh2[buf][p][tid][0] = wv;
        }
    };

    stage(0, 0);
    for (int kk = 0; kk < NK; ++kk) {
        const int buf = kk & 1;
        __syncthreads();
        bf16x8 af[4], bfv[8];
#pragma unroll
        for (int i = 0; i < 4; ++i)
            af[i] = *(const bf16x8*)&Ash[buf][l4][wt + i * 16 + l15][0];
#pragma unroll
        for (int j = 0; j < 8; ++j)
            bfv[j] = *(const bf16x8*)&Bsh2[buf][l4][wsi * 128 + j * 16 + l15][0];
        if (kk + 1 < NK) stage(kk + 1, buf ^ 1);
#pragma unroll
        for (int i = 0; i < 4; ++i)
#pragma unroll
            for (int j = 0; j < 8; ++j)
                acc[i][j] = __builtin_amdgcn_mfma_f32_16x16x32_bf16(af[i], bfv[j], acc[i][j], 0, 0, 0);
    }
#pragma unroll
    for (int i = 0; i < 4; ++i) {
        f32x4 v = acc[i][0];
#pragma unroll
        for (int j = 1; j < 8; ++j) {
            v.x = fmaxf(v.x, acc[i][j].x); v.y = fmaxf(v.y, acc[i][j].y);
            v.z = fmaxf(v.z, acc[i][j].z); v.w = fmaxf(v.w, acc[i][j].w);
        }
#pragma unroll
        for (int off = 1; off < 16; off <<= 1) {
            v.x = fmaxf(v.x, __shfl_xor(v.x, off, 64));
            v.y = fmaxf(v.y, __shfl_xor(v.y, off, 64));
            v.z = fmaxf(v.z, __shfl_xor(v.z, off, 64));
            v.w = fmaxf(v.w, __shfl_xor(v.w, off, 64));
        }
        if (l15 == 0) *(f32x4*)&maxbuf[wsi][wt + i * 16 + l4 * 4] = v;
    }
    __syncthreads();
    if (tid < 128) {
        float v = fmaxf(maxbuf[0][tid], maxbuf[1][tid]);
        out[((size_t)b * TT + t0 + tid) * NM + m] = tanhf(v);
    }
}

extern "C" void kernel_launch(void* const* d_in, const int* in_sizes, int n_in,
                              void* d_out, int out_size, void* d_ws, size_t ws_size,
                              hipStream_t stream) {
    const float* lt  = (const float*)d_in[0];   // (32,256,512) fp32
    const float* rt  = (const float*)d_in[1];   // (32,256,512) fp32
    const float* km  = (const float*)d_in[2];   // (20,512) fp32
    float*       out = (float*)d_out;           // (32,256,20) fp32

    const size_t elems = (size_t)NB * TT * DD;                  // 4,194,304 per tensor
    const size_t castB = 2 * elems * sizeof(unsigned short);    // 16 MB
    const int    nOut  = NB * TT * NM;                          // 163,840
    const size_t partB = 2 * (size_t)nOut * sizeof(float);      // 1.31 MB

    if (ws_size >= castB + partB) {
        unsigned short* ltb = (unsigned short*)d_ws;
        unsigned short* rtb = ltb + elems;
        float* part = (float*)((char*)d_ws + castB);
        cast_bf16<<<4096, 256, 0, stream>>>(lt, rt, ltb, rtb);
        mp_match_split<<<2560, 256, 0, stream>>>(ltb, rtb, km, part);
        mp_combine<<<(nOut + 255) / 256, 256, 0, stream>>>(part, out, nOut);
    } else {
        mp_match_kernel<<<dim3(2, NM, NB), 256, 0, stream>>>(lt, rt, km, out);
    }
}